// Round 3
// baseline (961.730 us; speedup 1.0000x reference)
//
#include <hip/hip_runtime.h>
#include <hip/hip_bf16.h>

typedef __attribute__((ext_vector_type(8))) short short8;
typedef __attribute__((ext_vector_type(4))) float f32x4;

#define T_STEPS 48
#define BATCH 32
#define EDIM 512
#define HDIM 1024
#define VOCAB 32000
#define GRU_BLOCKS 64

__device__ __forceinline__ unsigned short f2bf(float f) {
    __hip_bfloat16 h = __float2bfloat16(f);
    return *reinterpret_cast<unsigned short*>(&h);
}
__device__ __forceinline__ float bf2f(unsigned short u) {
    union { unsigned int i; float f; } v;
    v.i = ((unsigned int)u) << 16;
    return v.f;
}

// global -> LDS async copy, 16B per lane. LDS dest must be wave-uniform base;
// HW writes lane l's 16B at base + l*16. (CK-style addrspace casts; low 32 bits
// of a generic __shared__ address are the LDS byte offset.)
typedef __attribute__((address_space(1))) const void GAS;
typedef __attribute__((address_space(3))) void LAS;
__device__ __forceinline__ void gload_lds16(const unsigned short* g, unsigned short* l) {
    __builtin_amdgcn_global_load_lds((GAS*)g, (LAS*)(unsigned)(uintptr_t)l, 16, 0, 0);
}

// ---------------- prep: all fp32->bf16 conversions + embedding gather ----------------
__global__ __launch_bounds__(256) void prep_kernel(
    const float* __restrict__ h0, const int* __restrict__ tseq,
    const float* __restrict__ emb, const float* __restrict__ w_ih,
    const float* __restrict__ w_hh, const float* __restrict__ w_cls,
    unsigned short* __restrict__ wcls_bf, unsigned short* __restrict__ wih_bf,
    unsigned short* __restrict__ whh_hi, unsigned short* __restrict__ whh_lo,
    unsigned short* __restrict__ x_bf, unsigned short* __restrict__ hs_hi,
    unsigned short* __restrict__ hs_lo)
{
    const long R0 = (long)VOCAB * HDIM / 4;
    const long R1 = (long)3 * HDIM * EDIM / 4;
    const long R2 = (long)3 * HDIM * HDIM / 4;
    const long R3 = (long)T_STEPS * BATCH * EDIM / 4;
    const long R4 = (long)BATCH * HDIM / 4;
    const long total = R0 + R1 + R2 + R3 + R4;

    for (long i = (long)blockIdx.x * blockDim.x + threadIdx.x; i < total;
         i += (long)gridDim.x * blockDim.x) {
        if (i < R0) {
            float4 v = reinterpret_cast<const float4*>(w_cls)[i];
            ushort4 u = { f2bf(v.x), f2bf(v.y), f2bf(v.z), f2bf(v.w) };
            *reinterpret_cast<ushort4*>(wcls_bf + i * 4) = u;
        } else if (i < R0 + R1) {
            long j = i - R0;
            float4 v = reinterpret_cast<const float4*>(w_ih)[j];
            ushort4 u = { f2bf(v.x), f2bf(v.y), f2bf(v.z), f2bf(v.w) };
            *reinterpret_cast<ushort4*>(wih_bf + j * 4) = u;
        } else if (i < R0 + R1 + R2) {
            long j = i - R0 - R1;
            float4 v = reinterpret_cast<const float4*>(w_hh)[j];
            ushort4 hi = { f2bf(v.x), f2bf(v.y), f2bf(v.z), f2bf(v.w) };
            ushort4 lo = { f2bf(v.x - bf2f(hi.x)), f2bf(v.y - bf2f(hi.y)),
                           f2bf(v.z - bf2f(hi.z)), f2bf(v.w - bf2f(hi.w)) };
            *reinterpret_cast<ushort4*>(whh_hi + j * 4) = hi;
            *reinterpret_cast<ushort4*>(whh_lo + j * 4) = lo;
        } else if (i < R0 + R1 + R2 + R3) {
            long j = i - R0 - R1 - R2;
            int m = (int)(j >> 7);
            int kk4 = (int)(j & 127);
            int t = m >> 5, b = m & 31;
            int tok = tseq[b * T_STEPS + t];
            float4 v = reinterpret_cast<const float4*>(emb)[(long)tok * (EDIM / 4) + kk4];
            ushort4 u = { f2bf(v.x), f2bf(v.y), f2bf(v.z), f2bf(v.w) };
            *reinterpret_cast<ushort4*>(x_bf + (long)m * EDIM + kk4 * 4) = u;
        } else {
            long j = i - R0 - R1 - R2 - R3;
            float4 v = reinterpret_cast<const float4*>(h0)[j];
            ushort4 hi = { f2bf(v.x), f2bf(v.y), f2bf(v.z), f2bf(v.w) };
            ushort4 lo = { f2bf(v.x - bf2f(hi.x)), f2bf(v.y - bf2f(hi.y)),
                           f2bf(v.z - bf2f(hi.z)), f2bf(v.w - bf2f(hi.w)) };
            *reinterpret_cast<ushort4*>(hs_hi + j * 4) = hi;
            *reinterpret_cast<ushort4*>(hs_lo + j * 4) = lo;
        }
    }
}

// ---------------- bf16 MFMA GEMM (m97-style gload_lds staging) ----------------
// C[M][Ntot](+bias) = A[M][K] * B[N][K]^T. 128x128 tile, BK=32, 256 threads.
// 1D grid with bijective XCD swizzle; M-fastest tile order (12 consecutive wgs
// share one B panel -> stays in that XCD's L2).
template <bool SCORES>
__global__ __launch_bounds__(256) void gemm_lds(
    const unsigned short* __restrict__ A, const unsigned short* __restrict__ B,
    const float* __restrict__ bias, float* __restrict__ C, int K, int Ntot, int nM)
{
    const int nwg = gridDim.x;
    const int lin = blockIdx.x;
    const int q = nwg >> 3;                 // nwg % 8 == 0 in both uses
    const int wg = (lin & 7) * q + (lin >> 3);
    const int mi = wg % nM, ni = wg / nM;
    const int m0 = mi * 128, n0 = ni * 128;

    const int tid = threadIdx.x;
    const int lane = tid & 63;
    const int wid = tid >> 6;
    const int wr = wid >> 1, wc = wid & 1;

    __shared__ __align__(16) unsigned short As[128 * 32];
    __shared__ __align__(16) unsigned short Bs[128 * 32];

    f32x4 acc[4][4] = {};
    const int NT = K >> 5;
    const int srow = (lane >> 2);           // staging: row within 16-row chunk
    const int skk = (lane & 3) * 8;         // staging: k offset

    for (int kt = 0; kt < NT; ++kt) {
        __syncthreads();                    // previous tile consumed by all waves
        {
            const int kb = kt * 32;
#pragma unroll
            for (int h2 = 0; h2 < 2; ++h2) {
                const int i = wid + h2 * 4;                 // chunk id 0..7
                const int row = i * 16 + srow;
                gload_lds16(A + (size_t)(m0 + row) * K + kb + skk, As + i * 512);
                gload_lds16(B + (size_t)(n0 + row) * K + kb + skk, Bs + i * 512);
            }
        }
        __syncthreads();                    // compiler drains vmcnt(0) here -> tile ready

        const int kg = lane >> 4;
        const int l15 = lane & 15;
        short8 af[4], bf[4];
#pragma unroll
        for (int i = 0; i < 4; ++i) {
            af[i] = *(const short8*)(As + ((wr * 64 + i * 16 + l15) * 32 + kg * 8));
            bf[i] = *(const short8*)(Bs + ((wc * 64 + i * 16 + l15) * 32 + kg * 8));
        }
#pragma unroll
        for (int i = 0; i < 4; ++i)
#pragma unroll
            for (int j = 0; j < 4; ++j)
                acc[i][j] = __builtin_amdgcn_mfma_f32_16x16x32_bf16(af[i], bf[j], acc[i][j], 0, 0, 0);
    }

    const int l15 = lane & 15, lhi = lane >> 4;
#pragma unroll
    for (int i = 0; i < 4; ++i) {
#pragma unroll
        for (int j = 0; j < 4; ++j) {
            int col = n0 + wc * 64 + j * 16 + l15;
            float bv = bias[col];
#pragma unroll
            for (int q2 = 0; q2 < 4; ++q2) {
                int row = m0 + wr * 64 + i * 16 + lhi * 4 + q2;
                float v = acc[i][j][q2] + bv;
                if (SCORES) {
                    int t = row >> 5, b = row & 31;         // row = t*32+b
                    C[(size_t)(b * T_STEPS + t) * Ntot + col] = v;
                } else {
                    C[(size_t)row * Ntot + col] = v;
                }
            }
        }
    }
}

// ---------------- persistent GRU: all 48 steps in ONE launch ----------------
// 64 blocks (all co-resident on 256 CUs), device-scope atomic grid barrier
// between steps. Block owns 16 j's (all 3 gates). W_hh slices are re-read by
// the same block every step -> L2/L3-served instead of HBM.
__global__ __launch_bounds__(256) void gru_persist(
    unsigned short* __restrict__ hs_hi, unsigned short* __restrict__ hs_lo,
    const unsigned short* __restrict__ whh_hi, const unsigned short* __restrict__ whh_lo,
    const float* __restrict__ gi, const float* __restrict__ b_hh, int* __restrict__ bar)
{
    const int j0 = blockIdx.x * 16;
    const int tid = threadIdx.x;
    const int lane = tid & 63, wid = tid >> 6;
    const int l15 = lane & 15, kg = lane >> 4;

    __shared__ float P[4][32][48];

    for (int t = 0; t < T_STEPS; ++t) {
        const unsigned short* hA_hi = hs_hi + (size_t)t * BATCH * HDIM;
        const unsigned short* hA_lo = hs_lo + (size_t)t * BATCH * HDIM;

        f32x4 acc[2][3] = {};
        const int kq = wid * 256;
#pragma unroll
        for (int ks = 0; ks < 8; ++ks) {
            const int kb = kq + ks * 32 + kg * 8;
            short8 ahi[2], alo[2], bhi[3], blo[3];
#pragma unroll
            for (int mi2 = 0; mi2 < 2; ++mi2) {
                const size_t off = (size_t)(mi2 * 16 + l15) * HDIM + kb;
                ahi[mi2] = *(const short8*)(hA_hi + off);
                alo[mi2] = *(const short8*)(hA_lo + off);
            }
#pragma unroll
            for (int g = 0; g < 3; ++g) {
                const size_t off = (size_t)(g * HDIM + j0 + l15) * HDIM + kb;
                bhi[g] = *(const short8*)(whh_hi + off);
                blo[g] = *(const short8*)(whh_lo + off);
            }
#pragma unroll
            for (int mi2 = 0; mi2 < 2; ++mi2)
#pragma unroll
                for (int g = 0; g < 3; ++g) {
                    acc[mi2][g] = __builtin_amdgcn_mfma_f32_16x16x32_bf16(ahi[mi2], bhi[g], acc[mi2][g], 0, 0, 0);
                    acc[mi2][g] = __builtin_amdgcn_mfma_f32_16x16x32_bf16(ahi[mi2], blo[g], acc[mi2][g], 0, 0, 0);
                    acc[mi2][g] = __builtin_amdgcn_mfma_f32_16x16x32_bf16(alo[mi2], bhi[g], acc[mi2][g], 0, 0, 0);
                }
        }
        // scatter partials: C/D mapping col=lane&15, row=(lane>>4)*4+q
#pragma unroll
        for (int mi2 = 0; mi2 < 2; ++mi2)
#pragma unroll
            for (int g = 0; g < 3; ++g)
#pragma unroll
                for (int q = 0; q < 4; ++q)
                    P[wid][mi2 * 16 + kg * 4 + q][g * 16 + l15] = acc[mi2][g][q];
        __syncthreads();

#pragma unroll
        for (int it = 0; it < 2; ++it) {
            int item = tid + it * 256;
            int b = item >> 4, jj = item & 15;
            float ghr = 0.f, ghz = 0.f, ghn = 0.f;
#pragma unroll
            for (int w = 0; w < 4; ++w) {
                ghr += P[w][b][jj];
                ghz += P[w][b][16 + jj];
                ghn += P[w][b][32 + jj];
            }
            const int j = j0 + jj;
            ghr += b_hh[j];
            ghz += b_hh[HDIM + j];
            ghn += b_hh[2 * HDIM + j];
            const float* girow = gi + (size_t)(t * BATCH + b) * (3 * HDIM);
            float xr = girow[j], xz = girow[HDIM + j], xn = girow[2 * HDIM + j];
            float r = 1.f / (1.f + __expf(-(xr + ghr)));
            float z = 1.f / (1.f + __expf(-(xz + ghz)));
            float n = tanhf(xn + r * ghn);
            const size_t hoff = (size_t)b * HDIM + j;
            float hprev = bf2f(hA_hi[hoff]) + bf2f(hA_lo[hoff]);
            float hnew = (1.f - z) * n + z * hprev;
            unsigned short hi = f2bf(hnew);
            unsigned short lo = f2bf(hnew - bf2f(hi));
            const size_t o = (size_t)(t + 1) * BATCH * HDIM + hoff;
            hs_hi[o] = hi;
            hs_lo[o] = lo;
        }

        // ---- grid barrier (monotone counter + generation flag) ----
        __threadfence();                     // each thread releases its h-stores
        __syncthreads();
        if (tid == 0) {
            int v = __hip_atomic_fetch_add(bar, 1, __ATOMIC_ACQ_REL, __HIP_MEMORY_SCOPE_AGENT);
            if (v == GRU_BLOCKS * (t + 1) - 1) {
                __hip_atomic_store(bar + 1, t + 1, __ATOMIC_RELEASE, __HIP_MEMORY_SCOPE_AGENT);
            } else {
                while (__hip_atomic_load(bar + 1, __ATOMIC_ACQUIRE, __HIP_MEMORY_SCOPE_AGENT) < t + 1)
                    __builtin_amdgcn_s_sleep(1);
            }
        }
        __syncthreads();                     // also protects P reuse next iteration
    }
}

extern "C" void kernel_launch(void* const* d_in, const int* in_sizes, int n_in,
                              void* d_out, int out_size, void* d_ws, size_t ws_size,
                              hipStream_t stream) {
    const float* h0    = (const float*)d_in[0];
    const int*   tseq  = (const int*)d_in[1];
    const float* emb   = (const float*)d_in[2];
    const float* w_ih  = (const float*)d_in[3];
    const float* w_hh  = (const float*)d_in[4];
    const float* b_ih  = (const float*)d_in[5];
    const float* b_hh  = (const float*)d_in[6];
    const float* w_cls = (const float*)d_in[7];
    const float* b_cls = (const float*)d_in[8];
    float* out = (float*)d_out;

    char* w = (char*)d_ws;
    unsigned short* wcls_bf = (unsigned short*)w; w += (size_t)VOCAB * HDIM * 2;
    unsigned short* wih_bf  = (unsigned short*)w; w += (size_t)3 * HDIM * EDIM * 2;
    unsigned short* whh_hi  = (unsigned short*)w; w += (size_t)3 * HDIM * HDIM * 2;
    unsigned short* whh_lo  = (unsigned short*)w; w += (size_t)3 * HDIM * HDIM * 2;
    unsigned short* x_bf    = (unsigned short*)w; w += (size_t)T_STEPS * BATCH * EDIM * 2;
    unsigned short* hs_hi   = (unsigned short*)w; w += (size_t)(T_STEPS + 1) * BATCH * HDIM * 2;
    unsigned short* hs_lo   = (unsigned short*)w; w += (size_t)(T_STEPS + 1) * BATCH * HDIM * 2;
    float* gi               = (float*)w;          w += (size_t)T_STEPS * BATCH * 3 * HDIM * 4;
    int* bar                = (int*)w;            w += 256;

    hipMemsetAsync(bar, 0, 8, stream);

    prep_kernel<<<2048, 256, 0, stream>>>(h0, tseq, emb, w_ih, w_hh, w_cls,
                                          wcls_bf, wih_bf, whh_hi, whh_lo,
                                          x_bf, hs_hi, hs_lo);

    // GI = X @ W_ih^T + b_ih : M=1536, N=3072, K=512  (288 wgs, %8==0)
    gemm_lds<false><<<(T_STEPS * BATCH / 128) * (3 * HDIM / 128), 256, 0, stream>>>(
        x_bf, wih_bf, b_ih, gi, EDIM, 3 * HDIM, T_STEPS * BATCH / 128);

    // all 48 GRU steps in one persistent launch
    gru_persist<<<GRU_BLOCKS, 256, 0, stream>>>(hs_hi, hs_lo, whh_hi, whh_lo, gi, b_hh, bar);

    // scores = Hs[1..48] @ W_cls^T + b_cls : M=1536, N=32000, K=1024 (3000 wgs, %8==0)
    gemm_lds<true><<<(T_STEPS * BATCH / 128) * (VOCAB / 128), 256, 0, stream>>>(
        hs_hi + (size_t)BATCH * HDIM, wcls_bf, b_cls, out, HDIM, VOCAB, T_STEPS * BATCH / 128);
}